// Round 3
// baseline (1078.856 us; speedup 1.0000x reference)
//
#include <hip/hip_runtime.h>
#include <hip/hip_bf16.h>

// deformable_cross_grd_attention — MI355X/gfx950
// B=4, NQ=16384, EMBED=256, HEADS=8, HEAD_DIM=32, LEVELS=4, POINTS=4, NV=5440
//
// Pipeline: proj+GN per level -> value GEMM -> off/attw GEMMs (fp32 X, cast in
// staging) -> softmax -> bilinear sampler -> out GEMM (+2Q residual) ->
// FFN in two M-halves (lin1 relu -> lin2 -> LN+add).
//
// Workspace map (bytes; overlays time-sliced; PEAK TOUCH = 90,439,680 B ~86.3 MiB):
//   [0       , 983040  ) WT_* transposed bf16 weights (live whole launch)
//   [1048576 , 23330816) VAL fp32 (proj)     -> ATT bf16 [1048576,34603008) -> HID half
//   [23330816, 34471936) VALB bf16 (GN out)  -> (ATT/HID tail)
//   [34603008, 56885248) V fp32 (value GEMM) -> FUSEDB bf16 [34603008,68157440)
//   [56885248, 90439680) AW fp32 (attw+softmax) -> FUSEDB tail -> T16 bf16 half
//                                                  [68157440,84934656)
//   OFFS fp32 (64 MB) lives in d_out; dead before out-GEMM writes FUSED there.

#define NQc 16384
#define NVc 5440

typedef __attribute__((ext_vector_type(8))) short short8;
typedef __attribute__((ext_vector_type(4))) float f32x4;

__device__ __forceinline__ float wred(float v) {
#pragma unroll
  for (int o = 32; o > 0; o >>= 1) v += __shfl_down(v, o);
  return v;
}

// ---------------- weight transpose + cast:  W[K][N] fp32 -> Wt[N][K] bf16 ----
__global__ __launch_bounds__(256) void tcast_kernel(
    const float* __restrict__ w, __hip_bfloat16* __restrict__ wt, int K, int N) {
  int i = blockIdx.x * 256 + threadIdx.x;
  if (i < K * N) {
    int k = i / N, n = i - k * N;
    wt[(size_t)n * K + k] = __float2bfloat16(w[i]);
  }
}

// ---------------- per-level 1x1 conv projection -----------------------------
// block = one (b, nv) position, 256 threads = 256 output channels
__global__ __launch_bounds__(256) void proj_kernel(
    const float* __restrict__ g0, const float* __restrict__ g1,
    const float* __restrict__ g2, const float* __restrict__ g3,
    const float* __restrict__ w0, const float* __restrict__ w1,
    const float* __restrict__ w2, const float* __restrict__ w3,
    const float* __restrict__ pb0, const float* __restrict__ pb1,
    const float* __restrict__ pb2, const float* __restrict__ pb3,
    float* __restrict__ val) {
  const int bid = blockIdx.x;            // b*NV + nv
  const int b = bid / NVc;
  const int nv = bid - b * NVc;
  const float* gsrc; const float* w; const float* pb; int C, HW, hw;
  if (nv < 4096)      { gsrc = g0; w = w0; pb = pb0; C = 24;   HW = 4096; hw = nv; }
  else if (nv < 5120) { gsrc = g1; w = w1; pb = pb1; C = 40;   HW = 1024; hw = nv - 4096; }
  else if (nv < 5376) { gsrc = g2; w = w2; pb = pb2; C = 112;  HW = 256;  hw = nv - 5120; }
  else                { gsrc = g3; w = w3; pb = pb3; C = 1280; HW = 64;   hw = nv - 5376; }
  const int e = threadIdx.x;
  const float* gp = gsrc + (size_t)b * C * HW + hw;
  float a0 = 0.f, a1 = 0.f, a2 = 0.f, a3 = 0.f;
  for (int c = 0; c < C; c += 4) {       // C % 4 == 0 for all levels
    float x0 = gp[(size_t)(c + 0) * HW];
    float x1 = gp[(size_t)(c + 1) * HW];
    float x2 = gp[(size_t)(c + 2) * HW];
    float x3 = gp[(size_t)(c + 3) * HW];
    a0 += x0 * w[(c + 0) * 256 + e];
    a1 += x1 * w[(c + 1) * 256 + e];
    a2 += x2 * w[(c + 2) * 256 + e];
    a3 += x3 * w[(c + 3) * 256 + e];
  }
  val[(size_t)bid * 256 + e] = (a0 + a1) + (a2 + a3) + pb[e];
}

// ---------------- GroupNorm (32 groups of 8 ch) -> bf16 ---------------------
__global__ __launch_bounds__(256) void gn_kernel(
    const float* __restrict__ val, __hip_bfloat16* __restrict__ valb,
    const float* __restrict__ gg0, const float* __restrict__ gb0,
    const float* __restrict__ gg1, const float* __restrict__ gb1,
    const float* __restrict__ gg2, const float* __restrict__ gb2,
    const float* __restrict__ gg3, const float* __restrict__ gb3) {
  const int bid = blockIdx.x;            // b*128 + l*32 + grp
  const int grp = bid & 31;
  const int l = (bid >> 5) & 3;
  const int b = bid >> 7;
  int HW, start; const float *gg, *gbeta;
  if (l == 0)      { HW = 4096; start = 0;    gg = gg0; gbeta = gb0; }
  else if (l == 1) { HW = 1024; start = 4096; gg = gg1; gbeta = gb1; }
  else if (l == 2) { HW = 256;  start = 5120; gg = gg2; gbeta = gb2; }
  else             { HW = 64;   start = 5376; gg = gg3; gbeta = gb3; }
  const int n = HW * 8;
  const size_t base = ((size_t)(b * NVc + start)) * 256 + grp * 8;
  float s = 0.f, s2 = 0.f;
  for (int i = threadIdx.x; i < n; i += 256) {
    float x = val[base + (size_t)(i >> 3) * 256 + (i & 7)];
    s += x; s2 += x * x;
  }
  s = wred(s); s2 = wred(s2);
  __shared__ float red[8];
  const int wv = threadIdx.x >> 6;
  if ((threadIdx.x & 63) == 0) { red[wv] = s; red[4 + wv] = s2; }
  __syncthreads();
  const float S = red[0] + red[1] + red[2] + red[3];
  const float S2 = red[4] + red[5] + red[6] + red[7];
  const float inv_n = 1.f / (float)n;
  const float mu = S * inv_n;
  const float var = S2 * inv_n - mu * mu;
  const float rstd = rsqrtf(var + 1e-5f);
  for (int i = threadIdx.x; i < n; i += 256) {
    const int j = i & 7;
    const int e = grp * 8 + j;
    const size_t idx = base + (size_t)(i >> 3) * 256 + j;
    const float y = (val[idx] - mu) * rstd * gg[e] + gbeta[e];
    valb[idx] = __float2bfloat16(y);
  }
}

// ---------------- bf16 MFMA GEMM: C[M][N] = X[M][K] * Wt[N][K]^T + bias ------
// 128x128 tile, BK=64, 4 waves (2x2), 4x4 16x16x32 frags per wave.
// XF32: X is fp32, converted to bf16 during LDS staging.
// MODE 0: Cf = f32(acc+bias)
// MODE 1: Cb = bf16(relu(acc+bias))
// MODE 2: f = acc+bias+2*Qres; Cf = f; Cb = bf16(f)
// MODE 3: Cb = bf16(acc+bias)
template <int MODE, bool XF32>
__global__ __launch_bounds__(256) void gemm_bt(
    const void* __restrict__ Xv, const __hip_bfloat16* __restrict__ Wt,
    const float* __restrict__ bias, float* __restrict__ Cf,
    __hip_bfloat16* __restrict__ Cb, const float* __restrict__ Qres,
    int M, int N, int K) {
  const int m0 = blockIdx.x * 128;
  const int n0 = blockIdx.y * 128;
  const int tid = threadIdx.x;
  const int wave = tid >> 6;
  const int lane = tid & 63;
  const int wm = wave >> 1;
  const int wn = wave & 1;
  const int l15 = lane & 15;
  const int l4 = lane >> 4;
  __shared__ __align__(16) __hip_bfloat16 As[128 * 64];
  __shared__ __align__(16) __hip_bfloat16 Bs[128 * 64];
  f32x4 acc[4][4];
#pragma unroll
  for (int m = 0; m < 4; ++m)
#pragma unroll
    for (int n = 0; n < 4; ++n) acc[m][n] = (f32x4){0.f, 0.f, 0.f, 0.f};

  for (int k0 = 0; k0 < K; k0 += 64) {
#pragma unroll
    for (int j = 0; j < 4; ++j) {
      const int e = (j * 256 + tid) * 8;
      const int r = e >> 6;
      const int k = e & 63;
      if constexpr (XF32) {
        const float* Xf = (const float*)Xv;
        const float4 a = *reinterpret_cast<const float4*>(&Xf[(size_t)(m0 + r) * K + k0 + k]);
        const float4 b = *reinterpret_cast<const float4*>(&Xf[(size_t)(m0 + r) * K + k0 + k + 4]);
        union { __hip_bfloat16 h[8]; short8 v; } u;
        u.h[0] = __float2bfloat16(a.x); u.h[1] = __float2bfloat16(a.y);
        u.h[2] = __float2bfloat16(a.z); u.h[3] = __float2bfloat16(a.w);
        u.h[4] = __float2bfloat16(b.x); u.h[5] = __float2bfloat16(b.y);
        u.h[6] = __float2bfloat16(b.z); u.h[7] = __float2bfloat16(b.w);
        *reinterpret_cast<short8*>(&As[e]) = u.v;
      } else {
        const __hip_bfloat16* Xb = (const __hip_bfloat16*)Xv;
        *reinterpret_cast<short8*>(&As[e]) =
            *reinterpret_cast<const short8*>(&Xb[(size_t)(m0 + r) * K + k0 + k]);
      }
      *reinterpret_cast<short8*>(&Bs[e]) =
          *reinterpret_cast<const short8*>(&Wt[(size_t)(n0 + r) * K + k0 + k]);
    }
    __syncthreads();
#pragma unroll
    for (int ks = 0; ks < 2; ++ks) {
      short8 a[4], bfr[4];
#pragma unroll
      for (int m = 0; m < 4; ++m)
        a[m] = *reinterpret_cast<const short8*>(
            &As[(wm * 64 + m * 16 + l15) * 64 + ks * 32 + l4 * 8]);
#pragma unroll
      for (int n = 0; n < 4; ++n)
        bfr[n] = *reinterpret_cast<const short8*>(
            &Bs[(wn * 64 + n * 16 + l15) * 64 + ks * 32 + l4 * 8]);
#pragma unroll
      for (int m = 0; m < 4; ++m)
#pragma unroll
        for (int n = 0; n < 4; ++n)
          acc[m][n] = __builtin_amdgcn_mfma_f32_16x16x32_bf16(a[m], bfr[n], acc[m][n], 0, 0, 0);
    }
    __syncthreads();
  }

#pragma unroll
  for (int m = 0; m < 4; ++m) {
    const int row0 = m0 + wm * 64 + m * 16 + l4 * 4;
#pragma unroll
    for (int n = 0; n < 4; ++n) {
      const int col = n0 + wn * 64 + n * 16 + l15;
      const float bv = bias[col];
#pragma unroll
      for (int r = 0; r < 4; ++r) {
        const size_t ci = (size_t)(row0 + r) * N + col;
        float f = acc[m][n][r] + bv;
        if (MODE == 0) {
          Cf[ci] = f;
        } else if (MODE == 1) {
          Cb[ci] = __float2bfloat16(fmaxf(f, 0.f));
        } else if (MODE == 2) {
          f += 2.f * Qres[ci];
          Cf[ci] = f;
          Cb[ci] = __float2bfloat16(f);
        } else {
          Cb[ci] = __float2bfloat16(f);
        }
      }
    }
  }
}

// ---------------- softmax over 16 (one (b,q,h) row per thread) --------------
__global__ __launch_bounds__(256) void softmax_kernel(float* __restrict__ aw) {
  const size_t t = (size_t)blockIdx.x * 256 + threadIdx.x;
  float* p = aw + t * 16;
  float v[16];
  *reinterpret_cast<float4*>(&v[0])  = *reinterpret_cast<const float4*>(p + 0);
  *reinterpret_cast<float4*>(&v[4])  = *reinterpret_cast<const float4*>(p + 4);
  *reinterpret_cast<float4*>(&v[8])  = *reinterpret_cast<const float4*>(p + 8);
  *reinterpret_cast<float4*>(&v[12]) = *reinterpret_cast<const float4*>(p + 12);
  float mx = v[0];
#pragma unroll
  for (int j = 1; j < 16; ++j) mx = fmaxf(mx, v[j]);
  float sum = 0.f;
#pragma unroll
  for (int j = 0; j < 16; ++j) { v[j] = __expf(v[j] - mx); sum += v[j]; }
  const float inv = 1.f / sum;
#pragma unroll
  for (int j = 0; j < 16; ++j) v[j] *= inv;
  *reinterpret_cast<float4*>(p + 0)  = *reinterpret_cast<const float4*>(&v[0]);
  *reinterpret_cast<float4*>(p + 4)  = *reinterpret_cast<const float4*>(&v[4]);
  *reinterpret_cast<float4*>(p + 8)  = *reinterpret_cast<const float4*>(&v[8]);
  *reinterpret_cast<float4*>(p + 12) = *reinterpret_cast<const float4*>(&v[12]);
}

// ---------------- deformable bilinear sampler -------------------------------
// block = one (b,q); 256 threads = (8 heads x 32 dims). Output bf16 (B*NQ,256).
__global__ __launch_bounds__(256) void sampler_kernel(
    const float* __restrict__ V, const float* __restrict__ OFFS,
    const float* __restrict__ AW, __hip_bfloat16* __restrict__ ATT) {
  const int bid = blockIdx.x;            // b*NQ + q
  const int q = bid & (NQc - 1);
  const int b = bid >> 14;
  const int tid = threadIdx.x;
  const int h = tid >> 5;
  const int d = tid & 31;
  const float rx = (float)(q & 127) * (1.f / 127.f);
  const float ry = (float)(q >> 7) * (1.f / 127.f);
  const float* offs = OFFS + (size_t)bid * 256 + h * 32;
  const float* aw = AW + (size_t)bid * 128 + h * 16;
  const float* vbase = V + (size_t)b * (NVc * 256) + h * 32 + d;
  const int Ws[4] = {64, 32, 16, 8};
  const int starts[4] = {0, 4096, 5120, 5376};
  float acc = 0.f;
#pragma unroll
  for (int l = 0; l < 4; ++l) {
    const int W = Ws[l];
    const float* vl = vbase + (size_t)starts[l] * 256;
#pragma unroll
    for (int p = 0; p < 4; ++p) {
      const float ox = offs[l * 8 + p * 2 + 0];
      const float oy = offs[l * 8 + p * 2 + 1];
      const float w = aw[l * 4 + p];
      const float x = rx * (float)W + ox - 0.5f;   // == (rx + ox/W)*W - 0.5
      const float y = ry * (float)W + oy - 0.5f;
      const float x0f = floorf(x);
      const float y0f = floorf(y);
      const int x0 = (int)x0f;
      const int y0 = (int)y0f;
      const float dx = x - x0f;
      const float dy = y - y0f;
      const int x1 = x0 + 1, y1 = y0 + 1;
      const float mx0 = (x0 >= 0 && x0 < W) ? 1.f : 0.f;
      const float mx1 = (x1 >= 0 && x1 < W) ? 1.f : 0.f;
      const float my0 = (y0 >= 0 && y0 < W) ? 1.f : 0.f;
      const float my1 = (y1 >= 0 && y1 < W) ? 1.f : 0.f;
      const int x0c = min(max(x0, 0), W - 1);
      const int x1c = min(max(x1, 0), W - 1);
      const int y0c = min(max(y0, 0), W - 1);
      const int y1c = min(max(y1, 0), W - 1);
      const float v00 = vl[(size_t)(y0c * W + x0c) * 256] * (mx0 * my0);
      const float v01 = vl[(size_t)(y0c * W + x1c) * 256] * (mx1 * my0);
      const float v10 = vl[(size_t)(y1c * W + x0c) * 256] * (mx0 * my1);
      const float v11 = vl[(size_t)(y1c * W + x1c) * 256] * (mx1 * my1);
      const float sv = v00 * (1.f - dx) * (1.f - dy) + v01 * dx * (1.f - dy) +
                       v10 * (1.f - dx) * dy + v11 * dx * dy;
      acc += w * sv;
    }
  }
  ATT[(size_t)bid * 256 + tid] = __float2bfloat16(acc);
}

// ---------------- LayerNorm(T bf16) + add into out (out holds fused) --------
__global__ __launch_bounds__(256) void ln_add_kernel(
    const __hip_bfloat16* __restrict__ T, const float* __restrict__ lng,
    const float* __restrict__ lnb, float* __restrict__ out) {
  const size_t row = blockIdx.x;
  const int e = threadIdx.x;
  const float t = __bfloat162float(T[row * 256 + e]);
  float s = wred(t);
  float s2 = wred(t * t);
  __shared__ float red[8];
  const int wv = e >> 6;
  if ((e & 63) == 0) { red[wv] = s; red[4 + wv] = s2; }
  __syncthreads();
  const float S = red[0] + red[1] + red[2] + red[3];
  const float S2 = red[4] + red[5] + red[6] + red[7];
  const float mu = S * (1.f / 256.f);
  const float var = S2 * (1.f / 256.f) - mu * mu;
  const float y = (t - mu) * rsqrtf(var + 1e-5f) * lng[e] + lnb[e];
  out[row * 256 + e] += y;
}

extern "C" void kernel_launch(void* const* d_in, const int* in_sizes, int n_in,
                              void* d_out, int out_size, void* d_ws, size_t ws_size,
                              hipStream_t stream) {
  const float* Q  = (const float*)d_in[0];
  const float* g0 = (const float*)d_in[1];
  const float* g1 = (const float*)d_in[2];
  const float* g2 = (const float*)d_in[3];
  const float* g3 = (const float*)d_in[4];
  // d_in[5] = batch_size (fixed 4)
  const float* pw0 = (const float*)d_in[6];
  const float* pb0 = (const float*)d_in[7];
  const float* gg0 = (const float*)d_in[8];
  const float* gb0 = (const float*)d_in[9];
  const float* pw1 = (const float*)d_in[10];
  const float* pb1 = (const float*)d_in[11];
  const float* gg1 = (const float*)d_in[12];
  const float* gb1 = (const float*)d_in[13];
  const float* pw2 = (const float*)d_in[14];
  const float* pb2 = (const float*)d_in[15];
  const float* gg2 = (const float*)d_in[16];
  const float* gb2 = (const float*)d_in[17];
  const float* pw3 = (const float*)d_in[18];
  const float* pb3 = (const float*)d_in[19];
  const float* gg3 = (const float*)d_in[20];
  const float* gb3 = (const float*)d_in[21];
  const float* value_w = (const float*)d_in[22];
  const float* value_b = (const float*)d_in[23];
  const float* off_w   = (const float*)d_in[24];
  const float* off_b   = (const float*)d_in[25];
  const float* attw_w  = (const float*)d_in[26];
  const float* attw_b  = (const float*)d_in[27];
  const float* out_w   = (const float*)d_in[28];
  const float* out_b   = (const float*)d_in[29];
  const float* lin1_w  = (const float*)d_in[30];
  const float* lin1_b  = (const float*)d_in[31];
  const float* lin2_w  = (const float*)d_in[32];
  const float* lin2_b  = (const float*)d_in[33];
  const float* ln_g    = (const float*)d_in[34];
  const float* ln_b    = (const float*)d_in[35];

  char* ws = (char*)d_ws;
  __hip_bfloat16* WT_VALUE = (__hip_bfloat16*)(ws + 0);        // 131072
  __hip_bfloat16* WT_OFF   = (__hip_bfloat16*)(ws + 131072);   // 131072
  __hip_bfloat16* WT_ATTW  = (__hip_bfloat16*)(ws + 262144);   // 65536
  __hip_bfloat16* WT_OUT   = (__hip_bfloat16*)(ws + 327680);   // 131072
  __hip_bfloat16* WT_LIN1  = (__hip_bfloat16*)(ws + 458752);   // 262144
  __hip_bfloat16* WT_LIN2  = (__hip_bfloat16*)(ws + 720896);   // 262144 -> 983040
  float*          VAL      = (float*)(ws + 1048576);           // 22282240 -> 23330816
  __hip_bfloat16* VALB     = (__hip_bfloat16*)(ws + 23330816); // 11141120 -> 34471936
  float*          V        = (float*)(ws + 34603008);          // 22282240 -> 56885248
  float*          AW       = (float*)(ws + 56885248);          // 33554432 -> 90439680 (peak)
  __hip_bfloat16* ATT      = (__hip_bfloat16*)(ws + 1048576);  // 33554432 (VAL/VALB dead)
  __hip_bfloat16* FUSEDB   = (__hip_bfloat16*)(ws + 34603008); // 33554432 (V, AW-head dead)
  __hip_bfloat16* HIDH     = (__hip_bfloat16*)(ws + 1048576);  // 33554432 per half (ATT dead)
  __hip_bfloat16* T16H     = (__hip_bfloat16*)(ws + 68157440); // 16777216 per half (AW tail dead)
  float*          OFFS     = (float*)d_out;                    // 64MB, dead before FUSED
  float*          FUSED    = (float*)d_out;                    // fused residual -> final output

  // 1. weight transposes -> bf16 (N,K)
  tcast_kernel<<<256, 256, 0, stream>>>(value_w, WT_VALUE, 256, 256);
  tcast_kernel<<<256, 256, 0, stream>>>(off_w,   WT_OFF,   256, 256);
  tcast_kernel<<<128, 256, 0, stream>>>(attw_w,  WT_ATTW,  256, 128);
  tcast_kernel<<<256, 256, 0, stream>>>(out_w,   WT_OUT,   256, 256);
  tcast_kernel<<<512, 256, 0, stream>>>(lin1_w,  WT_LIN1,  256, 512);
  tcast_kernel<<<512, 256, 0, stream>>>(lin2_w,  WT_LIN2,  512, 256);

  // 2. value branch: proj -> GN(bf16) -> value GEMM
  proj_kernel<<<21760, 256, 0, stream>>>(g0, g1, g2, g3, pw0, pw1, pw2, pw3,
                                         pb0, pb1, pb2, pb3, VAL);
  gn_kernel<<<512, 256, 0, stream>>>(VAL, VALB, gg0, gb0, gg1, gb1, gg2, gb2, gg3, gb3);
  gemm_bt<0, false><<<dim3(170, 2), 256, 0, stream>>>(VALB, WT_VALUE, value_b, V,
                                                      nullptr, nullptr, 21760, 256, 256);

  // 3. query branch: offsets (-> d_out) + attention weights (+softmax); X = Q fp32
  gemm_bt<0, true><<<dim3(512, 2), 256, 0, stream>>>(Q, WT_OFF, off_b, OFFS,
                                                     nullptr, nullptr, 65536, 256, 256);
  gemm_bt<0, true><<<dim3(512, 1), 256, 0, stream>>>(Q, WT_ATTW, attw_b, AW,
                                                     nullptr, nullptr, 65536, 128, 256);
  softmax_kernel<<<2048, 256, 0, stream>>>(AW);

  // 4. deformable sampling -> ATT (bf16, overlays dead VAL/VALB)
  sampler_kernel<<<65536, 256, 0, stream>>>(V, OFFS, AW, ATT);

  // 5. out proj + 2Q residual: FUSED(f32, d_out; kills OFFS) + FUSEDB(bf16)
  gemm_bt<2, false><<<dim3(512, 2), 256, 0, stream>>>(ATT, WT_OUT, out_b, FUSED,
                                                      FUSEDB, Q, 65536, 256, 256);

  // 6. FFN in two M-halves of 32768 rows (keeps scratch small):
  //    lin1(relu)->HIDH (overlays dead ATT), lin2->T16H bf16, LN+add into FUSED.
  for (int h = 0; h < 2; ++h) {
    const __hip_bfloat16* Xh = FUSEDB + (size_t)h * 32768 * 256;
    gemm_bt<1, false><<<dim3(256, 4), 256, 0, stream>>>(Xh, WT_LIN1, lin1_b, nullptr,
                                                        HIDH, nullptr, 32768, 512, 256);
    gemm_bt<3, false><<<dim3(256, 2), 256, 0, stream>>>(HIDH, WT_LIN2, lin2_b, nullptr,
                                                        T16H, nullptr, 32768, 256, 512);
    ln_add_kernel<<<32768, 256, 0, stream>>>(T16H, ln_g, ln_b,
                                             FUSED + (size_t)h * 32768 * 256);
  }
}

// Round 4
// 774.699 us; speedup vs baseline: 1.3926x; 1.3926x over previous
//
#include <hip/hip_runtime.h>
#include <hip/hip_bf16.h>

// deformable_cross_grd_attention — MI355X/gfx950
// B=4, NQ=16384, EMBED=256, HEADS=8, HEAD_DIM=32, LEVELS=4, POINTS=4, NV=5440
//
// Pipeline: proj+GN per level -> value GEMM -> off/attw GEMMs (fp32 X, cast in
// staging) -> softmax -> bilinear sampler (2-phase: geometry->LDS, float4
// gather) -> out GEMM (+2Q residual) -> FFN in two M-halves.
//
// Workspace map (bytes; overlays time-sliced; PEAK TOUCH = 90,439,680 B ~86.3 MiB):
//   [0       , 983040  ) WT_* transposed bf16 weights (live whole launch)
//   [1048576 , 23330816) VAL fp32 (proj)     -> ATT bf16 [1048576,34603008) -> HID half
//   [23330816, 34471936) VALB bf16 (GN out)  -> (ATT/HID tail)
//   [34603008, 56885248) V fp32 (value GEMM) -> FUSEDB bf16 [34603008,68157440)
//   [56885248, 90439680) AW fp32 (attw+softmax) -> FUSEDB tail -> T16 bf16 half
//                                                  [68157440,84934656)
//   OFFS fp32 (64 MB) lives in d_out; dead before out-GEMM writes FUSED there.

#define NQc 16384
#define NVc 5440

typedef __attribute__((ext_vector_type(8))) short short8;
typedef __attribute__((ext_vector_type(4))) short short4v;
typedef __attribute__((ext_vector_type(4))) float f32x4;

__device__ __forceinline__ float wred(float v) {
#pragma unroll
  for (int o = 32; o > 0; o >>= 1) v += __shfl_down(v, o);
  return v;
}

// ---------------- weight transpose + cast:  W[K][N] fp32 -> Wt[N][K] bf16 ----
__global__ __launch_bounds__(256) void tcast_kernel(
    const float* __restrict__ w, __hip_bfloat16* __restrict__ wt, int K, int N) {
  int i = blockIdx.x * 256 + threadIdx.x;
  if (i < K * N) {
    int k = i / N, n = i - k * N;
    wt[(size_t)n * K + k] = __float2bfloat16(w[i]);
  }
}

// ---------------- per-level 1x1 conv projection -----------------------------
__global__ __launch_bounds__(256) void proj_kernel(
    const float* __restrict__ g0, const float* __restrict__ g1,
    const float* __restrict__ g2, const float* __restrict__ g3,
    const float* __restrict__ w0, const float* __restrict__ w1,
    const float* __restrict__ w2, const float* __restrict__ w3,
    const float* __restrict__ pb0, const float* __restrict__ pb1,
    const float* __restrict__ pb2, const float* __restrict__ pb3,
    float* __restrict__ val) {
  const int bid = blockIdx.x;            // b*NV + nv
  const int b = bid / NVc;
  const int nv = bid - b * NVc;
  const float* gsrc; const float* w; const float* pb; int C, HW, hw;
  if (nv < 4096)      { gsrc = g0; w = w0; pb = pb0; C = 24;   HW = 4096; hw = nv; }
  else if (nv < 5120) { gsrc = g1; w = w1; pb = pb1; C = 40;   HW = 1024; hw = nv - 4096; }
  else if (nv < 5376) { gsrc = g2; w = w2; pb = pb2; C = 112;  HW = 256;  hw = nv - 5120; }
  else                { gsrc = g3; w = w3; pb = pb3; C = 1280; HW = 64;   hw = nv - 5376; }
  const int e = threadIdx.x;
  const float* gp = gsrc + (size_t)b * C * HW + hw;
  float a0 = 0.f, a1 = 0.f, a2 = 0.f, a3 = 0.f;
  for (int c = 0; c < C; c += 4) {       // C % 4 == 0 for all levels
    float x0 = gp[(size_t)(c + 0) * HW];
    float x1 = gp[(size_t)(c + 1) * HW];
    float x2 = gp[(size_t)(c + 2) * HW];
    float x3 = gp[(size_t)(c + 3) * HW];
    a0 += x0 * w[(c + 0) * 256 + e];
    a1 += x1 * w[(c + 1) * 256 + e];
    a2 += x2 * w[(c + 2) * 256 + e];
    a3 += x3 * w[(c + 3) * 256 + e];
  }
  val[(size_t)bid * 256 + e] = (a0 + a1) + (a2 + a3) + pb[e];
}

// ---------------- GroupNorm (32 groups of 8 ch) -> bf16 ---------------------
__global__ __launch_bounds__(256) void gn_kernel(
    const float* __restrict__ val, __hip_bfloat16* __restrict__ valb,
    const float* __restrict__ gg0, const float* __restrict__ gb0,
    const float* __restrict__ gg1, const float* __restrict__ gb1,
    const float* __restrict__ gg2, const float* __restrict__ gb2,
    const float* __restrict__ gg3, const float* __restrict__ gb3) {
  const int bid = blockIdx.x;            // b*128 + l*32 + grp
  const int grp = bid & 31;
  const int l = (bid >> 5) & 3;
  const int b = bid >> 7;
  int HW, start; const float *gg, *gbeta;
  if (l == 0)      { HW = 4096; start = 0;    gg = gg0; gbeta = gb0; }
  else if (l == 1) { HW = 1024; start = 4096; gg = gg1; gbeta = gb1; }
  else if (l == 2) { HW = 256;  start = 5120; gg = gg2; gbeta = gb2; }
  else             { HW = 64;   start = 5376; gg = gg3; gbeta = gb3; }
  const int n = HW * 8;
  const size_t base = ((size_t)(b * NVc + start)) * 256 + grp * 8;
  float s = 0.f, s2 = 0.f;
  for (int i = threadIdx.x; i < n; i += 256) {
    float x = val[base + (size_t)(i >> 3) * 256 + (i & 7)];
    s += x; s2 += x * x;
  }
  s = wred(s); s2 = wred(s2);
  __shared__ float red[8];
  const int wv = threadIdx.x >> 6;
  if ((threadIdx.x & 63) == 0) { red[wv] = s; red[4 + wv] = s2; }
  __syncthreads();
  const float S = red[0] + red[1] + red[2] + red[3];
  const float S2 = red[4] + red[5] + red[6] + red[7];
  const float inv_n = 1.f / (float)n;
  const float mu = S * inv_n;
  const float var = S2 * inv_n - mu * mu;
  const float rstd = rsqrtf(var + 1e-5f);
  for (int i = threadIdx.x; i < n; i += 256) {
    const int j = i & 7;
    const int e = grp * 8 + j;
    const size_t idx = base + (size_t)(i >> 3) * 256 + j;
    const float y = (val[idx] - mu) * rstd * gg[e] + gbeta[e];
    valb[idx] = __float2bfloat16(y);
  }
}

// ---------------- bf16 MFMA GEMM: C[M][N] = X[M][K] * Wt[N][K]^T + bias ------
// 128x128 tile, BK=64, 4 waves (2x2), 4x4 16x16x32 frags per wave.
// XF32: X is fp32, converted to bf16 during LDS staging.
// MODE 0: Cf = f32(acc+bias)
// MODE 1: Cb = bf16(relu(acc+bias))
// MODE 2: f = acc+bias+2*Qres; Cf = f; Cb = bf16(f)
// MODE 3: Cb = bf16(acc+bias)
template <int MODE, bool XF32>
__global__ __launch_bounds__(256) void gemm_bt(
    const void* __restrict__ Xv, const __hip_bfloat16* __restrict__ Wt,
    const float* __restrict__ bias, float* __restrict__ Cf,
    __hip_bfloat16* __restrict__ Cb, const float* __restrict__ Qres,
    int M, int N, int K) {
  const int m0 = blockIdx.x * 128;
  const int n0 = blockIdx.y * 128;
  const int tid = threadIdx.x;
  const int wave = tid >> 6;
  const int lane = tid & 63;
  const int wm = wave >> 1;
  const int wn = wave & 1;
  const int l15 = lane & 15;
  const int l4 = lane >> 4;
  __shared__ __align__(16) __hip_bfloat16 As[128 * 64];
  __shared__ __align__(16) __hip_bfloat16 Bs[128 * 64];
  f32x4 acc[4][4];
#pragma unroll
  for (int m = 0; m < 4; ++m)
#pragma unroll
    for (int n = 0; n < 4; ++n) acc[m][n] = (f32x4){0.f, 0.f, 0.f, 0.f};

  for (int k0 = 0; k0 < K; k0 += 64) {
#pragma unroll
    for (int j = 0; j < 4; ++j) {
      const int e = (j * 256 + tid) * 8;
      const int r = e >> 6;
      const int k = e & 63;
      if constexpr (XF32) {
        const float* Xf = (const float*)Xv;
        const float4 a = *reinterpret_cast<const float4*>(&Xf[(size_t)(m0 + r) * K + k0 + k]);
        const float4 b = *reinterpret_cast<const float4*>(&Xf[(size_t)(m0 + r) * K + k0 + k + 4]);
        union { __hip_bfloat16 h[8]; short8 v; } u;
        u.h[0] = __float2bfloat16(a.x); u.h[1] = __float2bfloat16(a.y);
        u.h[2] = __float2bfloat16(a.z); u.h[3] = __float2bfloat16(a.w);
        u.h[4] = __float2bfloat16(b.x); u.h[5] = __float2bfloat16(b.y);
        u.h[6] = __float2bfloat16(b.z); u.h[7] = __float2bfloat16(b.w);
        *reinterpret_cast<short8*>(&As[e]) = u.v;
      } else {
        const __hip_bfloat16* Xb = (const __hip_bfloat16*)Xv;
        *reinterpret_cast<short8*>(&As[e]) =
            *reinterpret_cast<const short8*>(&Xb[(size_t)(m0 + r) * K + k0 + k]);
      }
      *reinterpret_cast<short8*>(&Bs[e]) =
          *reinterpret_cast<const short8*>(&Wt[(size_t)(n0 + r) * K + k0 + k]);
    }
    __syncthreads();
#pragma unroll
    for (int ks = 0; ks < 2; ++ks) {
      short8 a[4], bfr[4];
#pragma unroll
      for (int m = 0; m < 4; ++m)
        a[m] = *reinterpret_cast<const short8*>(
            &As[(wm * 64 + m * 16 + l15) * 64 + ks * 32 + l4 * 8]);
#pragma unroll
      for (int n = 0; n < 4; ++n)
        bfr[n] = *reinterpret_cast<const short8*>(
            &Bs[(wn * 64 + n * 16 + l15) * 64 + ks * 32 + l4 * 8]);
#pragma unroll
      for (int m = 0; m < 4; ++m)
#pragma unroll
        for (int n = 0; n < 4; ++n)
          acc[m][n] = __builtin_amdgcn_mfma_f32_16x16x32_bf16(a[m], bfr[n], acc[m][n], 0, 0, 0);
    }
    __syncthreads();
  }

#pragma unroll
  for (int m = 0; m < 4; ++m) {
    const int row0 = m0 + wm * 64 + m * 16 + l4 * 4;
#pragma unroll
    for (int n = 0; n < 4; ++n) {
      const int col = n0 + wn * 64 + n * 16 + l15;
      const float bv = bias[col];
#pragma unroll
      for (int r = 0; r < 4; ++r) {
        const size_t ci = (size_t)(row0 + r) * N + col;
        float f = acc[m][n][r] + bv;
        if (MODE == 0) {
          Cf[ci] = f;
        } else if (MODE == 1) {
          Cb[ci] = __float2bfloat16(fmaxf(f, 0.f));
        } else if (MODE == 2) {
          f += 2.f * Qres[ci];
          Cf[ci] = f;
          Cb[ci] = __float2bfloat16(f);
        } else {
          Cb[ci] = __float2bfloat16(f);
        }
      }
    }
  }
}

// ---------------- softmax over 16 (one (b,q,h) row per thread) --------------
__global__ __launch_bounds__(256) void softmax_kernel(float* __restrict__ aw) {
  const size_t t = (size_t)blockIdx.x * 256 + threadIdx.x;
  float* p = aw + t * 16;
  float v[16];
  *reinterpret_cast<float4*>(&v[0])  = *reinterpret_cast<const float4*>(p + 0);
  *reinterpret_cast<float4*>(&v[4])  = *reinterpret_cast<const float4*>(p + 4);
  *reinterpret_cast<float4*>(&v[8])  = *reinterpret_cast<const float4*>(p + 8);
  *reinterpret_cast<float4*>(&v[12]) = *reinterpret_cast<const float4*>(p + 12);
  float mx = v[0];
#pragma unroll
  for (int j = 1; j < 16; ++j) mx = fmaxf(mx, v[j]);
  float sum = 0.f;
#pragma unroll
  for (int j = 0; j < 16; ++j) { v[j] = __expf(v[j] - mx); sum += v[j]; }
  const float inv = 1.f / sum;
#pragma unroll
  for (int j = 0; j < 16; ++j) v[j] *= inv;
  *reinterpret_cast<float4*>(p + 0)  = *reinterpret_cast<const float4*>(&v[0]);
  *reinterpret_cast<float4*>(p + 4)  = *reinterpret_cast<const float4*>(&v[4]);
  *reinterpret_cast<float4*>(p + 8)  = *reinterpret_cast<const float4*>(&v[8]);
  *reinterpret_cast<float4*>(p + 12) = *reinterpret_cast<const float4*>(&v[12]);
}

// ---------------- deformable bilinear sampler (2-phase) ---------------------
// block = 4 queries; 256 threads.
// Phase 1: 512 jobs = (q,h,tap): compute 4 clamped flat indices + 4 weights
//          (aw * bilinear * validity) once, store to LDS.
// Phase 2: thread = (q, h, dquad): float4 of 4 head-dims; 16 taps of
//          2x ds_read_b128 (broadcast) + 4x global_load_dwordx4 + 16 FMA.
__global__ __launch_bounds__(256) void sampler_kernel(
    const float* __restrict__ V, const float* __restrict__ OFFS,
    const float* __restrict__ AW, __hip_bfloat16* __restrict__ ATT) {
  __shared__ int   sIdx[512 * 4];
  __shared__ float sW[512 * 4];
  const int blk = blockIdx.x;              // [0, B*NQ/4)
  const int b = blk >> 12;                 // NQ/4 = 4096 blocks per batch
  const int q0 = (blk & 4095) << 2;        // within-batch first query
  const int bid0 = blk << 2;               // global row (b*NQ + q0)

  // ---- phase 1: geometry ----
  for (int j = threadIdx.x; j < 512; j += 256) {
    const int q   = j >> 7;                // 0..3
    const int h   = (j >> 4) & 7;
    const int tap = j & 15;                // l*4 + p
    const int l = tap >> 2, p = tap & 3;
    const int gq = bid0 + q;
    const int qq = q0 + q;
    const float rx = (float)(qq & 127) * (1.f / 127.f);
    const float ry = (float)(qq >> 7) * (1.f / 127.f);
    const float2 oxy = *reinterpret_cast<const float2*>(
        &OFFS[(size_t)gq * 256 + h * 32 + tap * 2]);
    const float aw = AW[(size_t)gq * 128 + h * 16 + tap];
    const int W = 64 >> l;
    const int start = (l & 2) ? ((l & 1) ? 5376 : 5120) : ((l & 1) ? 4096 : 0);
    const float fW = (float)W;
    const float x = rx * fW + oxy.x - 0.5f;
    const float y = ry * fW + oxy.y - 0.5f;
    const float x0f = floorf(x);
    const float y0f = floorf(y);
    const int x0 = (int)x0f;
    const int y0 = (int)y0f;
    const float dx = x - x0f;
    const float dy = y - y0f;
    const int x1 = x0 + 1, y1 = y0 + 1;
    const float mx0 = (x0 >= 0 && x0 < W) ? 1.f : 0.f;
    const float mx1 = (x1 >= 0 && x1 < W) ? 1.f : 0.f;
    const float my0 = (y0 >= 0 && y0 < W) ? 1.f : 0.f;
    const float my1 = (y1 >= 0 && y1 < W) ? 1.f : 0.f;
    const int x0c = min(max(x0, 0), W - 1);
    const int x1c = min(max(x1, 0), W - 1);
    const int y0c = min(max(y0, 0), W - 1);
    const int y1c = min(max(y1, 0), W - 1);
    int4 I;
    I.x = start + y0c * W + x0c;
    I.y = start + y0c * W + x1c;
    I.z = start + y1c * W + x0c;
    I.w = start + y1c * W + x1c;
    float4 Wv;
    Wv.x = aw * (1.f - dx) * (1.f - dy) * (mx0 * my0);
    Wv.y = aw * dx * (1.f - dy) * (mx1 * my0);
    Wv.z = aw * (1.f - dx) * dy * (mx0 * my1);
    Wv.w = aw * dx * dy * (mx1 * my1);
    *reinterpret_cast<int4*>(&sIdx[j * 4]) = I;
    *reinterpret_cast<float4*>(&sW[j * 4]) = Wv;
  }
  __syncthreads();

  // ---- phase 2: gather ----
  const int q  = threadIdx.x >> 6;         // 0..3
  const int h  = (threadIdx.x >> 3) & 7;   // 0..7
  const int dq = threadIdx.x & 7;          // 0..7 (covers 4 dims each)
  const float* vb = V + (size_t)b * (NVc * 256) + h * 32 + dq * 4;
  const int jbase = (q * 8 + h) * 16;
  f32x4 acc = (f32x4){0.f, 0.f, 0.f, 0.f};
#pragma unroll
  for (int tap = 0; tap < 16; ++tap) {
    const int4   I  = *reinterpret_cast<const int4*>(&sIdx[(jbase + tap) * 4]);
    const float4 Wv = *reinterpret_cast<const float4*>(&sW[(jbase + tap) * 4]);
    const f32x4 v00 = *reinterpret_cast<const f32x4*>(vb + ((size_t)I.x << 8));
    const f32x4 v01 = *reinterpret_cast<const f32x4*>(vb + ((size_t)I.y << 8));
    const f32x4 v10 = *reinterpret_cast<const f32x4*>(vb + ((size_t)I.z << 8));
    const f32x4 v11 = *reinterpret_cast<const f32x4*>(vb + ((size_t)I.w << 8));
    acc += v00 * Wv.x;
    acc += v01 * Wv.y;
    acc += v10 * Wv.z;
    acc += v11 * Wv.w;
  }
  union { __hip_bfloat16 hh[4]; short4v v; } u;
  u.hh[0] = __float2bfloat16(acc.x);
  u.hh[1] = __float2bfloat16(acc.y);
  u.hh[2] = __float2bfloat16(acc.z);
  u.hh[3] = __float2bfloat16(acc.w);
  *reinterpret_cast<short4v*>(
      &ATT[(size_t)(bid0 + q) * 256 + h * 32 + dq * 4]) = u.v;
}

// ---------------- LayerNorm(T bf16) + add into out (out holds fused) --------
__global__ __launch_bounds__(256) void ln_add_kernel(
    const __hip_bfloat16* __restrict__ T, const float* __restrict__ lng,
    const float* __restrict__ lnb, float* __restrict__ out) {
  const size_t row = blockIdx.x;
  const int e = threadIdx.x;
  const float t = __bfloat162float(T[row * 256 + e]);
  float s = wred(t);
  float s2 = wred(t * t);
  __shared__ float red[8];
  const int wv = e >> 6;
  if ((e & 63) == 0) { red[wv] = s; red[4 + wv] = s2; }
  __syncthreads();
  const float S = red[0] + red[1] + red[2] + red[3];
  const float S2 = red[4] + red[5] + red[6] + red[7];
  const float mu = S * (1.f / 256.f);
  const float var = S2 * (1.f / 256.f) - mu * mu;
  const float y = (t - mu) * rsqrtf(var + 1e-5f) * lng[e] + lnb[e];
  out[row * 256 + e] += y;
}

extern "C" void kernel_launch(void* const* d_in, const int* in_sizes, int n_in,
                              void* d_out, int out_size, void* d_ws, size_t ws_size,
                              hipStream_t stream) {
  const float* Q  = (const float*)d_in[0];
  const float* g0 = (const float*)d_in[1];
  const float* g1 = (const float*)d_in[2];
  const float* g2 = (const float*)d_in[3];
  const float* g3 = (const float*)d_in[4];
  // d_in[5] = batch_size (fixed 4)
  const float* pw0 = (const float*)d_in[6];
  const float* pb0 = (const float*)d_in[7];
  const float* gg0 = (const float*)d_in[8];
  const float* gb0 = (const float*)d_in[9];
  const float* pw1 = (const float*)d_in[10];
  const float* pb1 = (const float*)d_in[11];
  const float* gg1 = (const float*)d_in[12];
  const float* gb1 = (const float*)d_in[13];
  const float* pw2 = (const float*)d_in[14];
  const float* pb2 = (const float*)d_in[15];
  const float* gg2 = (const float*)d_in[16];
  const float* gb2 = (const float*)d_in[17];
  const float* pw3 = (const float*)d_in[18];
  const float* pb3 = (const float*)d_in[19];
  const float* gg3 = (const float*)d_in[20];
  const float* gb3 = (const float*)d_in[21];
  const float* value_w = (const float*)d_in[22];
  const float* value_b = (const float*)d_in[23];
  const float* off_w   = (const float*)d_in[24];
  const float* off_b   = (const float*)d_in[25];
  const float* attw_w  = (const float*)d_in[26];
  const float* attw_b  = (const float*)d_in[27];
  const float* out_w   = (const float*)d_in[28];
  const float* out_b   = (const float*)d_in[29];
  const float* lin1_w  = (const float*)d_in[30];
  const float* lin1_b  = (const float*)d_in[31];
  const float* lin2_w  = (const float*)d_in[32];
  const float* lin2_b  = (const float*)d_in[33];
  const float* ln_g    = (const float*)d_in[34];
  const float* ln_b    = (const float*)d_in[35];

  char* ws = (char*)d_ws;
  __hip_bfloat16* WT_VALUE = (__hip_bfloat16*)(ws + 0);        // 131072
  __hip_bfloat16* WT_OFF   = (__hip_bfloat16*)(ws + 131072);   // 131072
  __hip_bfloat16* WT_ATTW  = (__hip_bfloat16*)(ws + 262144);   // 65536
  __hip_bfloat16* WT_OUT   = (__hip_bfloat16*)(ws + 327680);   // 131072
  __hip_bfloat16* WT_LIN1  = (__hip_bfloat16*)(ws + 458752);   // 262144
  __hip_bfloat16* WT_LIN2  = (__hip_bfloat16*)(ws + 720896);   // 262144 -> 983040
  float*          VAL      = (float*)(ws + 1048576);           // 22282240 -> 23330816
  __hip_bfloat16* VALB     = (__hip_bfloat16*)(ws + 23330816); // 11141120 -> 34471936
  float*          V        = (float*)(ws + 34603008);          // 22282240 -> 56885248
  float*          AW       = (float*)(ws + 56885248);          // 33554432 -> 90439680 (peak)
  __hip_bfloat16* ATT      = (__hip_bfloat16*)(ws + 1048576);  // 33554432 (VAL/VALB dead)
  __hip_bfloat16* FUSEDB   = (__hip_bfloat16*)(ws + 34603008); // 33554432 (V, AW-head dead)
  __hip_bfloat16* HIDH     = (__hip_bfloat16*)(ws + 1048576);  // 33554432 per half (ATT dead)
  __hip_bfloat16* T16H     = (__hip_bfloat16*)(ws + 68157440); // 16777216 per half (AW tail dead)
  float*          OFFS     = (float*)d_out;                    // 64MB, dead before FUSED
  float*          FUSED    = (float*)d_out;                    // fused residual -> final output

  // 1. weight transposes -> bf16 (N,K)
  tcast_kernel<<<256, 256, 0, stream>>>(value_w, WT_VALUE, 256, 256);
  tcast_kernel<<<256, 256, 0, stream>>>(off_w,   WT_OFF,   256, 256);
  tcast_kernel<<<128, 256, 0, stream>>>(attw_w,  WT_ATTW,  256, 128);
  tcast_kernel<<<256, 256, 0, stream>>>(out_w,   WT_OUT,   256, 256);
  tcast_kernel<<<512, 256, 0, stream>>>(lin1_w,  WT_LIN1,  256, 512);
  tcast_kernel<<<512, 256, 0, stream>>>(lin2_w,  WT_LIN2,  512, 256);

  // 2. value branch: proj -> GN(bf16) -> value GEMM
  proj_kernel<<<21760, 256, 0, stream>>>(g0, g1, g2, g3, pw0, pw1, pw2, pw3,
                                         pb0, pb1, pb2, pb3, VAL);
  gn_kernel<<<512, 256, 0, stream>>>(VAL, VALB, gg0, gb0, gg1, gb1, gg2, gb2, gg3, gb3);
  gemm_bt<0, false><<<dim3(170, 2), 256, 0, stream>>>(VALB, WT_VALUE, value_b, V,
                                                      nullptr, nullptr, 21760, 256, 256);

  // 3. query branch: offsets (-> d_out) + attention weights (+softmax); X = Q fp32
  gemm_bt<0, true><<<dim3(512, 2), 256, 0, stream>>>(Q, WT_OFF, off_b, OFFS,
                                                     nullptr, nullptr, 65536, 256, 256);
  gemm_bt<0, true><<<dim3(512, 1), 256, 0, stream>>>(Q, WT_ATTW, attw_b, AW,
                                                     nullptr, nullptr, 65536, 128, 256);
  softmax_kernel<<<2048, 256, 0, stream>>>(AW);

  // 4. deformable sampling -> ATT (bf16, overlays dead VAL/VALB)
  sampler_kernel<<<16384, 256, 0, stream>>>(V, OFFS, AW, ATT);

  // 5. out proj + 2Q residual: FUSED(f32, d_out; kills OFFS) + FUSEDB(bf16)
  gemm_bt<2, false><<<dim3(512, 2), 256, 0, stream>>>(ATT, WT_OUT, out_b, FUSED,
                                                      FUSEDB, Q, 65536, 256, 256);

  // 6. FFN in two M-halves of 32768 rows (keeps scratch small):
  //    lin1(relu)->HIDH (overlays dead ATT), lin2->T16H bf16, LN+add into FUSED.
  for (int h = 0; h < 2; ++h) {
    const __hip_bfloat16* Xh = FUSEDB + (size_t)h * 32768 * 256;
    gemm_bt<1, false><<<dim3(256, 4), 256, 0, stream>>>(Xh, WT_LIN1, lin1_b, nullptr,
                                                        HIDH, nullptr, 32768, 512, 256);
    gemm_bt<3, false><<<dim3(256, 2), 256, 0, stream>>>(HIDH, WT_LIN2, lin2_b, nullptr,
                                                        T16H, nullptr, 32768, 256, 512);
    ln_add_kernel<<<32768, 256, 0, stream>>>(T16H, ln_g, ln_b,
                                             FUSED + (size_t)h * 32768 * 256);
  }
}